// Round 12
// baseline (145.812 us; speedup 1.0000x reference)
//
#include <hip/hip_runtime.h>
#include <hip/hip_bf16.h>
#include <math.h>

#define BB 64
#define NN 128
#define DD 32
#define PP (NN * (NN - 1))   // 16256
#define EPSF 1e-5f

typedef __attribute__((ext_vector_type(8))) short bf16x8;
typedef __attribute__((ext_vector_type(4))) float f32x4;

static __device__ __forceinline__ unsigned short f2bf(float x) {
    unsigned u = __builtin_bit_cast(unsigned, x);
    u += 0x7fff + ((u >> 16) & 1);          // RNE
    return (unsigned short)(u >> 16);
}
static __device__ __forceinline__ unsigned pk2bf(float a, float b) {
    float2 t; t.x = a; t.y = b;
    __hip_bfloat162 h = __float22bfloat162_rn(t);   // v_cvt_pk_bf16_f32
    unsigned u;
    __builtin_memcpy(&u, &h, 4);
    return u;
}
static __device__ __forceinline__ float leakyf(float x) {
    return fmaxf(x, 0.01f * x);
}

// ============ Kernel 1: proj + per-node partial sums + pack + zero ============
__global__ __launch_bounds__(256) void proj_kernel(
    const float* __restrict__ inputs, const float* __restrict__ W1,
    const float* __restrict__ b1,
    const float* __restrict__ W2, const float* __restrict__ W3,
    float* __restrict__ AT, float* __restrict__ BT,
    unsigned short* __restrict__ ATh, unsigned short* __restrict__ BTh,
    float* __restrict__ SQp,
    unsigned short* __restrict__ W2p, unsigned short* __restrict__ W3p,
    float* __restrict__ fpartA, float* __restrict__ fpartB)
{
    __shared__ float Xs[16 * 33];
    __shared__ float W1s[2048];
    __shared__ float red[16];

    int tid = threadIdx.x;
    int n = blockIdx.x >> 2, q = blockIdx.x & 3;

    for (int idx = tid; idx < 2048; idx += 256) W1s[idx] = W1[idx];
    for (int idx = tid; idx < 512; idx += 256) {
        int r = idx >> 5, d = idx & 31;
        Xs[r * 33 + d] = inputs[(size_t)(q * 16 + r) * 4096 + n * 32 + d];
    }
    __syncthreads();

    int j = tid & 31, rb = tid >> 5;
    int lane = tid & 63, w = tid >> 6;
    float b1j = b1[j];
    float sa = 0.f, qa = 0.f, sb = 0.f, qb = 0.f;
    #pragma unroll
    for (int i = 0; i < 2; ++i) {
        int r = rb * 2 + i;
        int b = q * 16 + r;
        float a = b1j, c = 0.f;
        #pragma unroll
        for (int k = 0; k < 32; ++k) {
            float x = Xs[r * 33 + k];
            a += x * W1s[k * 32 + j];
            c += x * W1s[(32 + k) * 32 + j];
        }
        size_t off = ((size_t)n * 64 + b) * 32 + j;
        AT[off] = a;  BT[off] = c;
        ATh[off] = f2bf(a);  BTh[off] = f2bf(c);
        sa += a; qa += a * a; sb += c; qb += c * c;
    }
    #pragma unroll
    for (int d = 32; d > 0; d >>= 1) {
        sa += __shfl_down(sa, d, 64);
        qa += __shfl_down(qa, d, 64);
        sb += __shfl_down(sb, d, 64);
        qb += __shfl_down(qb, d, 64);
    }
    if (lane == 0) { red[w*4+0] = sa; red[w*4+1] = qa; red[w*4+2] = sb; red[w*4+3] = qb; }
    __syncthreads();
    if (tid == 0) {
        float4 v;
        v.x = red[0] + red[4] + red[8]  + red[12];
        v.y = red[1] + red[5] + red[9]  + red[13];
        v.z = red[2] + red[6] + red[10] + red[14];
        v.w = red[3] + red[7] + red[11] + red[15];
        ((float4*)SQp)[n * 4 + q] = v;
    }

    if (blockIdx.x == 0 && tid < 64) {      // pack W2/W3 -> bf16 B-frag layout
        int l = tid, nn2 = l & 15, kc = l >> 4;
        #pragma unroll
        for (int ct = 0; ct < 2; ++ct)
            #pragma unroll
            for (int jj = 0; jj < 8; ++jj) {
                int k = kc * 8 + jj;
                W2p[(ct * 64 + l) * 8 + jj] = f2bf(W2[k * 32 + ct * 16 + nn2]);
            }
        #pragma unroll
        for (int ct = 0; ct < 3; ++ct)
            #pragma unroll
            for (int jj = 0; jj < 8; ++jj) {
                int k = kc * 8 + jj;
                int c2 = ct * 16 + nn2;
                W3p[(ct * 64 + l) * 8 + jj] = f2bf(c2 < 33 ? W3[k * 33 + c2] : 0.f);
            }
    }
    if (blockIdx.x == 1) {
        for (int idx = tid; idx < 1024; idx += 256) {
            fpartA[idx] = 0.f;
            fpartB[idx] = 0.f;
        }
    }
}

// ============ Kernel 2: LN stats via bf16 MFMA cross-GEMM ============
// Writes interleaved (sc, sh) pairs -> one dwordx2 load in edges.
__global__ __launch_bounds__(256) void stats2_kernel(
    const unsigned short* __restrict__ ATh, const unsigned short* __restrict__ BTh,
    const float* __restrict__ SQp,
    const float* __restrict__ g1, const float* __restrict__ be1,
    float* __restrict__ statAB)
{
    __shared__ __align__(16) float part[4 * 64 * 4];
    int tid = threadIdx.x;
    int lane = tid & 63, w = tid >> 6;
    int s0 = (blockIdx.x >> 3) * 16, t0 = (blockIdx.x & 7) * 16;

    int m = lane & 15, kc = lane >> 4;
    const unsigned short* abase = ATh + (size_t)(s0 + m) * 2048 + kc * 8 + w * 512;
    const unsigned short* bbase = BTh + (size_t)(t0 + m) * 2048 + kc * 8 + w * 512;

    f32x4 acc0 = {0.f, 0.f, 0.f, 0.f}, acc1 = {0.f, 0.f, 0.f, 0.f};
    #pragma unroll
    for (int step = 0; step < 8; ++step) {
        bf16x8 av0 = *(const bf16x8*)(abase + (2 * step) * 32);
        bf16x8 bv0 = *(const bf16x8*)(bbase + (2 * step) * 32);
        acc0 = __builtin_amdgcn_mfma_f32_16x16x32_bf16(av0, bv0, acc0, 0, 0, 0);
        bf16x8 av1 = *(const bf16x8*)(abase + (2 * step + 1) * 32);
        bf16x8 bv1 = *(const bf16x8*)(bbase + (2 * step + 1) * 32);
        acc1 = __builtin_amdgcn_mfma_f32_16x16x32_bf16(av1, bv1, acc1, 0, 0, 0);
    }
    f32x4 acc;
    acc[0] = acc0[0] + acc1[0]; acc[1] = acc0[1] + acc1[1];
    acc[2] = acc0[2] + acc1[2]; acc[3] = acc0[3] + acc1[3];
    *(f32x4*)&part[(w * 64 + lane) * 4] = acc;
    __syncthreads();

    if (w == 0) {
        #pragma unroll
        for (int ww = 1; ww < 4; ++ww) {
            f32x4 o2 = *(const f32x4*)&part[(ww * 64 + lane) * 4];
            acc[0] += o2[0]; acc[1] += o2[1]; acc[2] += o2[2]; acc[3] += o2[3];
        }
        int col = lane & 15, quad = lane >> 4;
        int t = t0 + col;
        float sbt = 0.f, qbt = 0.f;
        #pragma unroll
        for (int o2 = 0; o2 < 4; ++o2) {
            float4 v = ((const float4*)SQp)[t * 4 + o2];
            sbt += v.z; qbt += v.w;
        }
        #pragma unroll
        for (int r = 0; r < 4; ++r) {
            int s = s0 + quad * 4 + r;
            if (s != t) {
                float sas = 0.f, qas = 0.f;
                #pragma unroll
                for (int o2 = 0; o2 < 4; ++o2) {
                    float4 v = ((const float4*)SQp)[s * 4 + o2];
                    sas += v.x; qas += v.y;
                }
                int e = t - (t > s);
                int p = s * 127 + e;
                float S = sas + sbt;
                float Q = qas + qbt + 2.f * acc[r];
                float mean = S * (1.f / 2048.f);
                float var  = Q * (1.f / 2048.f) - mean * mean;
                float inv  = rsqrtf(var + EPSF);
                float sc   = inv * g1[p];
                float2 st;
                st.x = sc;
                st.y = be1[p] - mean * sc;
                ((float2*)statAB)[p] = st;
            }
        }
    }
}

// ============ Kernel 3: edge MLP, wave-private pipeline, b-PAIR per block ====
// 4096 blocks: s = bx&127, b0 = (bx>>7)*2. 4 waves x 2 row-tiles x 2 batches.
// Setup (W-frags, biases, stats, Wf1) amortized over both batches. ONE barrier.
__global__ __launch_bounds__(256) void edges_kernel(
    const float* __restrict__ AT, const float* __restrict__ BT,
    const float* __restrict__ statAB,
    const unsigned short* __restrict__ W2p, const unsigned short* __restrict__ W3p,
    const float* __restrict__ b2, const float* __restrict__ b3,
    const float* __restrict__ inputs, const float* __restrict__ Wf1,
    const float* __restrict__ bf1,
    float* __restrict__ edges_out,
    float* __restrict__ f, float* __restrict__ fpartA, float* __restrict__ fpartB)
{
    __shared__ __align__(16) unsigned short Hs[4][512];   // per-wave 16x32 swizzled
    __shared__ float Wf1s[1024];
    __shared__ float aggbuf[2][4][32];

    int tid = threadIdx.x;
    int s = blockIdx.x & 127;
    int b0 = (blockIdx.x >> 7) * 2;
    int lane = tid & 63, w = tid >> 6;
    int m = lane & 15;          // A-frag row within tile / C-frag col
    int kb = lane >> 4;         // k-block (8 wide)
    int col = m;
    int q4 = kb * 4;            // C-frag row group
    int qbase = lane & 48;

    for (int idx = tid; idx < 1024; idx += 256) Wf1s[idx] = Wf1[idx];

    // B fragments + biases (block-invariant)
    bf16x8 wb2[2], wb3[3];
    wb2[0] = *(const bf16x8*)(W2p + (0 * 64 + lane) * 8);
    wb2[1] = *(const bf16x8*)(W2p + (1 * 64 + lane) * 8);
    wb3[0] = *(const bf16x8*)(W3p + (0 * 64 + lane) * 8);
    wb3[1] = *(const bf16x8*)(W3p + (1 * 64 + lane) * 8);
    wb3[2] = *(const bf16x8*)(W3p + (2 * 64 + lane) * 8);
    float b2c0 = b2[col], b2c1 = b2[16 + col];
    float b3c[3];
    #pragma unroll
    for (int ct = 0; ct < 3; ++ct) {
        int c = ct * 16 + col;
        b3c[ct] = (c < 33) ? b3[c] : 0.f;
    }

    // per-row-tile invariants (b-independent): edge id, target, LN stats
    int tr[2];
    float sc_[2], sh_[2];
    bool valid_[2];
    int grow_[2];
    #pragma unroll
    for (int rt = 0; rt < 2; ++rt) {
        int tile = w * 2 + rt;
        int e = tile * 16 + m;
        bool valid = (e < 127);
        int ee = valid ? e : 0;
        tr[rt] = ee + (ee >= s);
        valid_[rt] = valid;
        grow_[rt] = tile * 16 + q4;
        float2 st = ((const float2*)statAB)[s * 127 + ee];
        sc_[rt] = st.x; sh_[rt] = st.y;
    }

    float aggpart[2][3] = {{0.f,0.f,0.f},{0.f,0.f,0.f}};

    #pragma unroll
    for (int bsel = 0; bsel < 2; ++bsel) {
        int b = b0 + bsel;
        const float4* asl = (const float4*)(AT + ((size_t)s * 64 + b) * 32 + kb * 8);
        float4 a0 = asl[0], a1 = asl[1];

        #pragma unroll
        for (int rt = 0; rt < 2; ++rt) {
            float sc = sc_[rt], sh = sh_[rt];
            const float4* bsl = (const float4*)(BT + ((size_t)tr[rt] * 64 + b) * 32 + kb * 8);
            float4 bv0 = bsl[0], bv1 = bsl[1];

            float nh[8];
            nh[0] = leakyf((a0.x + bv0.x) * sc + sh);
            nh[1] = leakyf((a0.y + bv0.y) * sc + sh);
            nh[2] = leakyf((a0.z + bv0.z) * sc + sh);
            nh[3] = leakyf((a0.w + bv0.w) * sc + sh);
            nh[4] = leakyf((a1.x + bv1.x) * sc + sh);
            nh[5] = leakyf((a1.y + bv1.y) * sc + sh);
            nh[6] = leakyf((a1.z + bv1.z) * sc + sh);
            nh[7] = leakyf((a1.w + bv1.w) * sc + sh);
            if (!valid_[rt]) {
                #pragma unroll
                for (int q = 0; q < 8; ++q) nh[q] = 0.f;
            }
            union { bf16x8 v; unsigned u[4]; } AF;
            #pragma unroll
            for (int q = 0; q < 4; ++q) AF.u[q] = pk2bf(nh[2*q], nh[2*q+1]);

            // GEMM2: h2 tile (C layout)
            f32x4 c0 = {0.f, 0.f, 0.f, 0.f}, c1 = {0.f, 0.f, 0.f, 0.f};
            c0 = __builtin_amdgcn_mfma_f32_16x16x32_bf16(AF.v, wb2[0], c0, 0, 0, 0);
            c1 = __builtin_amdgcn_mfma_f32_16x16x32_bf16(AF.v, wb2[1], c1, 0, 0, 0);

            // C -> A transpose via wave-private swizzled scratch (no barrier)
            #pragma unroll
            for (int reg = 0; reg < 4; ++reg) {
                int row = q4 + reg;
                float x = leakyf(c0[reg] + b2c0);
                float y = leakyf(c1[reg] + b2c1);
                int cA = col;            // < 16
                int cB = col + 16;
                Hs[w][row * 32 + (((cA >> 3) ^ (row >> 2)) & 3) * 8 + (cA & 7)] = f2bf(x);
                Hs[w][row * 32 + (((cB >> 3) ^ (row >> 2)) & 3) * 8 + (cB & 7)] = f2bf(y);
            }
            // wave-synchronous read-back (compiler emits lgkmcnt wait)
            bf16x8 a2 = *(const bf16x8*)&Hs[w][m * 32 + ((kb ^ (m >> 2)) & 3) * 8];

            // GEMM3
            f32x4 oo[3];
            #pragma unroll
            for (int ct = 0; ct < 3; ++ct) {
                f32x4 cc = {0.f, 0.f, 0.f, 0.f};
                oo[ct] = __builtin_amdgcn_mfma_f32_16x16x32_bf16(a2, wb3[ct], cc, 0, 0, 0);
            }

            // sigmoid on col 0 lanes; quad broadcast via shfl
            float v0 = 0.f, v1 = 0.f, v2 = 0.f, v3 = 0.f;
            int grow0 = grow_[rt];
            if (col == 0) {
                v0 = 1.f / (1.f + __expf(-(oo[0][0] + b3c[0])));
                v1 = 1.f / (1.f + __expf(-(oo[0][1] + b3c[0])));
                v2 = 1.f / (1.f + __expf(-(oo[0][2] + b3c[0])));
                v3 = (grow0 == 124) ? 0.f
                   : 1.f / (1.f + __expf(-(oo[0][3] + b3c[0])));
                float* ep = edges_out + (size_t)b * PP + s * 127 + grow0;
                ep[0] = v0; ep[1] = v1; ep[2] = v2;
                if (grow0 != 124) ep[3] = v3;
            }
            float ev0 = __shfl(v0, qbase, 64);
            float ev1 = __shfl(v1, qbase, 64);
            float ev2 = __shfl(v2, qbase, 64);
            float ev3 = __shfl(v3, qbase, 64);

            // agg partials (cols 1..32 of the 48-wide output)
            #pragma unroll
            for (int ct = 0; ct < 3; ++ct) {
                float bb3 = b3c[ct];
                float pt = ev0 * (oo[ct][0] + bb3) + ev1 * (oo[ct][1] + bb3)
                         + ev2 * (oo[ct][2] + bb3) + ev3 * (oo[ct][3] + bb3);
                aggpart[bsel][ct] += pt;
            }
        }

        // quad-reduce agg partials, store wave slice for this batch
        #pragma unroll
        for (int ct = 0; ct < 3; ++ct) {
            float pt = aggpart[bsel][ct];
            pt += __shfl_xor(pt, 16, 64);
            pt += __shfl_xor(pt, 32, 64);
            int c = ct * 16 + col;
            if (kb == 0 && c >= 1 && c <= 32) aggbuf[bsel][w][c - 1] = pt;
        }
    }
    __syncthreads();                                   // the ONLY barrier

    // f-rows for both batches
    if (tid < 32) {
        int bsel = tid >> 4, j = tid & 15;
        size_t row = (size_t)(b0 + bsel) * 128 + s;
        const float* xrow = inputs + row * 32;
        float acc = bf1[j];
        #pragma unroll
        for (int k = 0; k < 32; ++k) acc += xrow[k] * Wf1s[k * 16 + j];
        #pragma unroll
        for (int k = 0; k < 32; ++k) {
            float tot = aggbuf[bsel][0][k] + aggbuf[bsel][1][k]
                      + aggbuf[bsel][2][k] + aggbuf[bsel][3][k];
            acc += tot * Wf1s[(32 + k) * 16 + j];
        }
        f[row * 16 + j] = acc;
        int bucket = ((blockIdx.x << 1) + bsel) & 63;
        atomicAdd(&fpartA[bucket * 16 + j], acc);
        atomicAdd(&fpartB[bucket * 16 + j], acc * acc);
    }
}

// ============ Kernel 4: f-stats reduce (redundant per block) + out ============
__global__ __launch_bounds__(256) void out_kernel(
    const float* __restrict__ f,
    const float* __restrict__ fpartA, const float* __restrict__ fpartB,
    const float* __restrict__ gf, const float* __restrict__ bef,
    const float* __restrict__ Wf2, const float* __restrict__ bf2,
    float* __restrict__ outp)
{
    __shared__ float Wf2s[512];
    __shared__ float sc[16], sh[16];
    __shared__ float fs[128];

    int tid = threadIdx.x;
    for (int idx = tid; idx < 512; idx += 256) Wf2s[idx] = Wf2[idx];
    if (tid < 16) {
        float S = 0.f, Q = 0.f;
        #pragma unroll
        for (int g = 0; g < 64; ++g) {
            S += fpartA[g * 16 + tid];
            Q += fpartB[g * 16 + tid];
        }
        float mean = S * (1.f / 8192.f);
        float var  = Q * (1.f / 8192.f) - mean * mean;
        float inv  = rsqrtf(var + EPSF);
        float s2   = inv * gf[tid];
        sc[tid] = s2;
        sh[tid] = bef[tid] - mean * s2;
    }
    int row0 = blockIdx.x * 8;
    if (tid < 128) {
        int r = tid >> 4, j = tid & 15;
        fs[r * 16 + j] = f[(size_t)(row0 + r) * 16 + j];
    }
    __syncthreads();

    int rl = tid >> 5, d = tid & 31;
    float acc = bf2[d];
    #pragma unroll
    for (int j = 0; j < 16; ++j) {
        float v = fs[rl * 16 + j] * sc[j] + sh[j];
        v = leakyf(v);
        acc += v * Wf2s[j * 32 + d];
    }
    outp[(size_t)(row0 + rl) * 32 + d] = acc;
}

extern "C" void kernel_launch(void* const* d_in, const int* in_sizes, int n_in,
                              void* d_out, int out_size, void* d_ws, size_t ws_size,
                              hipStream_t stream) {
    const float* inputs = (const float*)d_in[0];
    const float* W1   = (const float*)d_in[3];
    const float* b1   = (const float*)d_in[4];
    const float* g1   = (const float*)d_in[5];
    const float* be1  = (const float*)d_in[6];
    const float* W2   = (const float*)d_in[7];
    const float* b2   = (const float*)d_in[8];
    const float* W3   = (const float*)d_in[9];
    const float* b3   = (const float*)d_in[10];
    const float* Wf1  = (const float*)d_in[11];
    const float* bf1  = (const float*)d_in[12];
    const float* gf   = (const float*)d_in[13];
    const float* bef  = (const float*)d_in[14];
    const float* Wf2  = (const float*)d_in[15];
    const float* bf2  = (const float*)d_in[16];

    float* ws = (float*)d_ws;
    float* AT     = ws;                              // 262144
    float* BT     = ws + 262144;                     // 262144
    unsigned short* ATh = (unsigned short*)(ws + 524288);  // 262144 ush
    unsigned short* BTh = ATh + 262144;                    // 262144 ush
    float* SQp    = ws + 786432;                     // 2048
    float* statAB = ws + 790528;                     // 2*16256 = 32512
    float* f      = ws + 823040;                     // 131072
    float* fpartA = ws + 954112;                     // 1024
    float* fpartB = ws + 955136;                     // 1024
    unsigned short* W2p = (unsigned short*)(ws + 956160);  // 1024 ush
    unsigned short* W3p = W2p + 1024;                      // 1536 ush

    float* edges_out = (float*)d_out;                    // B*P
    float* outp      = edges_out + (size_t)BB * PP;      // B*N*D

    proj_kernel<<<512, 256, 0, stream>>>(inputs, W1, b1, W2, W3,
                                         AT, BT, ATh, BTh, SQp,
                                         W2p, W3p, fpartA, fpartB);
    stats2_kernel<<<64, 256, 0, stream>>>(ATh, BTh, SQp, g1, be1, statAB);
    edges_kernel<<<4096, 256, 0, stream>>>(AT, BT, statAB, W2p, W3p,
                                           b2, b3, inputs, Wf1, bf1,
                                           edges_out, f, fpartA, fpartB);
    out_kernel<<<1024, 256, 0, stream>>>(f, fpartA, fpartB, gf, bef, Wf2, bf2, outp);
}

// Round 13
// 143.002 us; speedup vs baseline: 1.0197x; 1.0197x over previous
//
#include <hip/hip_runtime.h>
#include <hip/hip_bf16.h>
#include <math.h>

#define BB 64
#define NN 128
#define DD 32
#define PP (NN * (NN - 1))   // 16256
#define EPSF 1e-5f

typedef __attribute__((ext_vector_type(8))) short bf16x8;
typedef __attribute__((ext_vector_type(4))) float f32x4;

static __device__ __forceinline__ unsigned short f2bf(float x) {
    unsigned u = __builtin_bit_cast(unsigned, x);
    u += 0x7fff + ((u >> 16) & 1);          // RNE
    return (unsigned short)(u >> 16);
}
static __device__ __forceinline__ unsigned pk2bf(float a, float b) {
    float2 t; t.x = a; t.y = b;
    __hip_bfloat162 h = __float22bfloat162_rn(t);   // v_cvt_pk_bf16_f32
    unsigned u;
    __builtin_memcpy(&u, &h, 4);
    return u;
}
static __device__ __forceinline__ float leakyf(float x) {
    return fmaxf(x, 0.01f * x);
}

// ============ Kernel 1: proj + per-node partial sums + pack + zero ============
__global__ __launch_bounds__(256) void proj_kernel(
    const float* __restrict__ inputs, const float* __restrict__ W1,
    const float* __restrict__ b1,
    const float* __restrict__ W2, const float* __restrict__ W3,
    float* __restrict__ AT, float* __restrict__ BT,
    unsigned short* __restrict__ ATh, unsigned short* __restrict__ BTh,
    float* __restrict__ SQp,
    unsigned short* __restrict__ W2p, unsigned short* __restrict__ W3p,
    float* __restrict__ fpartA, float* __restrict__ fpartB)
{
    __shared__ float Xs[16 * 33];
    __shared__ float W1s[2048];
    __shared__ float red[16];

    int tid = threadIdx.x;
    int n = blockIdx.x >> 2, q = blockIdx.x & 3;

    for (int idx = tid; idx < 2048; idx += 256) W1s[idx] = W1[idx];
    for (int idx = tid; idx < 512; idx += 256) {
        int r = idx >> 5, d = idx & 31;
        Xs[r * 33 + d] = inputs[(size_t)(q * 16 + r) * 4096 + n * 32 + d];
    }
    __syncthreads();

    int j = tid & 31, rb = tid >> 5;
    int lane = tid & 63, w = tid >> 6;
    float b1j = b1[j];
    float sa = 0.f, qa = 0.f, sb = 0.f, qb = 0.f;
    #pragma unroll
    for (int i = 0; i < 2; ++i) {
        int r = rb * 2 + i;
        int b = q * 16 + r;
        float a = b1j, c = 0.f;
        #pragma unroll
        for (int k = 0; k < 32; ++k) {
            float x = Xs[r * 33 + k];
            a += x * W1s[k * 32 + j];
            c += x * W1s[(32 + k) * 32 + j];
        }
        size_t off = ((size_t)n * 64 + b) * 32 + j;
        AT[off] = a;  BT[off] = c;
        ATh[off] = f2bf(a);  BTh[off] = f2bf(c);
        sa += a; qa += a * a; sb += c; qb += c * c;
    }
    #pragma unroll
    for (int d = 32; d > 0; d >>= 1) {
        sa += __shfl_down(sa, d, 64);
        qa += __shfl_down(qa, d, 64);
        sb += __shfl_down(sb, d, 64);
        qb += __shfl_down(qb, d, 64);
    }
    if (lane == 0) { red[w*4+0] = sa; red[w*4+1] = qa; red[w*4+2] = sb; red[w*4+3] = qb; }
    __syncthreads();
    if (tid == 0) {
        float4 v;
        v.x = red[0] + red[4] + red[8]  + red[12];
        v.y = red[1] + red[5] + red[9]  + red[13];
        v.z = red[2] + red[6] + red[10] + red[14];
        v.w = red[3] + red[7] + red[11] + red[15];
        ((float4*)SQp)[n * 4 + q] = v;
    }

    if (blockIdx.x == 0 && tid < 64) {      // pack W2/W3 -> bf16 B-frag layout
        int l = tid, nn2 = l & 15, kc = l >> 4;
        #pragma unroll
        for (int ct = 0; ct < 2; ++ct)
            #pragma unroll
            for (int jj = 0; jj < 8; ++jj) {
                int k = kc * 8 + jj;
                W2p[(ct * 64 + l) * 8 + jj] = f2bf(W2[k * 32 + ct * 16 + nn2]);
            }
        #pragma unroll
        for (int ct = 0; ct < 3; ++ct)
            #pragma unroll
            for (int jj = 0; jj < 8; ++jj) {
                int k = kc * 8 + jj;
                int c2 = ct * 16 + nn2;
                W3p[(ct * 64 + l) * 8 + jj] = f2bf(c2 < 33 ? W3[k * 33 + c2] : 0.f);
            }
    }
    if (blockIdx.x == 1) {
        for (int idx = tid; idx < 1024; idx += 256) {
            fpartA[idx] = 0.f;
            fpartB[idx] = 0.f;
        }
    }
}

// ============ Kernel 2: LN stats via bf16 MFMA cross-GEMM ============
// Writes interleaved (sc, sh) pairs -> one dwordx2 load in edges.
__global__ __launch_bounds__(256) void stats2_kernel(
    const unsigned short* __restrict__ ATh, const unsigned short* __restrict__ BTh,
    const float* __restrict__ SQp,
    const float* __restrict__ g1, const float* __restrict__ be1,
    float* __restrict__ statAB)
{
    __shared__ __align__(16) float part[4 * 64 * 4];
    int tid = threadIdx.x;
    int lane = tid & 63, w = tid >> 6;
    int s0 = (blockIdx.x >> 3) * 16, t0 = (blockIdx.x & 7) * 16;

    int m = lane & 15, kc = lane >> 4;
    const unsigned short* abase = ATh + (size_t)(s0 + m) * 2048 + kc * 8 + w * 512;
    const unsigned short* bbase = BTh + (size_t)(t0 + m) * 2048 + kc * 8 + w * 512;

    f32x4 acc0 = {0.f, 0.f, 0.f, 0.f}, acc1 = {0.f, 0.f, 0.f, 0.f};
    #pragma unroll
    for (int step = 0; step < 8; ++step) {
        bf16x8 av0 = *(const bf16x8*)(abase + (2 * step) * 32);
        bf16x8 bv0 = *(const bf16x8*)(bbase + (2 * step) * 32);
        acc0 = __builtin_amdgcn_mfma_f32_16x16x32_bf16(av0, bv0, acc0, 0, 0, 0);
        bf16x8 av1 = *(const bf16x8*)(abase + (2 * step + 1) * 32);
        bf16x8 bv1 = *(const bf16x8*)(bbase + (2 * step + 1) * 32);
        acc1 = __builtin_amdgcn_mfma_f32_16x16x32_bf16(av1, bv1, acc1, 0, 0, 0);
    }
    f32x4 acc;
    acc[0] = acc0[0] + acc1[0]; acc[1] = acc0[1] + acc1[1];
    acc[2] = acc0[2] + acc1[2]; acc[3] = acc0[3] + acc1[3];
    *(f32x4*)&part[(w * 64 + lane) * 4] = acc;
    __syncthreads();

    if (w == 0) {
        #pragma unroll
        for (int ww = 1; ww < 4; ++ww) {
            f32x4 o2 = *(const f32x4*)&part[(ww * 64 + lane) * 4];
            acc[0] += o2[0]; acc[1] += o2[1]; acc[2] += o2[2]; acc[3] += o2[3];
        }
        int col = lane & 15, quad = lane >> 4;
        int t = t0 + col;
        float sbt = 0.f, qbt = 0.f;
        #pragma unroll
        for (int o2 = 0; o2 < 4; ++o2) {
            float4 v = ((const float4*)SQp)[t * 4 + o2];
            sbt += v.z; qbt += v.w;
        }
        #pragma unroll
        for (int r = 0; r < 4; ++r) {
            int s = s0 + quad * 4 + r;
            if (s != t) {
                float sas = 0.f, qas = 0.f;
                #pragma unroll
                for (int o2 = 0; o2 < 4; ++o2) {
                    float4 v = ((const float4*)SQp)[s * 4 + o2];
                    sas += v.x; qas += v.y;
                }
                int e = t - (t > s);
                int p = s * 127 + e;
                float S = sas + sbt;
                float Q = qas + qbt + 2.f * acc[r];
                float mean = S * (1.f / 2048.f);
                float var  = Q * (1.f / 2048.f) - mean * mean;
                float inv  = rsqrtf(var + EPSF);
                float sc   = inv * g1[p];
                float2 st;
                st.x = sc;
                st.y = be1[p] - mean * sc;
                ((float2*)statAB)[p] = st;
            }
        }
    }
}

// ============ Kernel 3: edge MLP, wave-private pipeline, ONE barrier =========
// 8192 blocks: s = bx&127, b = bx>>7. 4 waves x 2 row-tiles of 16 edges.
// (R11 structure -- best measured; + float2 stats + pk-converted epilogue)
__global__ __launch_bounds__(256) void edges_kernel(
    const float* __restrict__ AT, const float* __restrict__ BT,
    const float* __restrict__ statAB,
    const unsigned short* __restrict__ W2p, const unsigned short* __restrict__ W3p,
    const float* __restrict__ b2, const float* __restrict__ b3,
    const float* __restrict__ inputs, const float* __restrict__ Wf1,
    const float* __restrict__ bf1,
    float* __restrict__ edges_out,
    float* __restrict__ f, float* __restrict__ fpartA, float* __restrict__ fpartB)
{
    __shared__ __align__(16) unsigned short Hs[4][512];   // per-wave 16x32 swizzled
    __shared__ float Wf1s[1024];
    __shared__ float aggbuf[4][32];

    int tid = threadIdx.x;
    int s = blockIdx.x & 127;
    int b = blockIdx.x >> 7;
    int lane = tid & 63, w = tid >> 6;
    int m = lane & 15;          // A-frag row within tile / C-frag col
    int kb = lane >> 4;         // k-block (8 wide)
    int col = m;
    int q4 = kb * 4;            // C-frag row group
    int qbase = lane & 48;

    for (int idx = tid; idx < 1024; idx += 256) Wf1s[idx] = Wf1[idx];

    // B fragments + biases (block-invariant)
    bf16x8 wb2[2], wb3[3];
    wb2[0] = *(const bf16x8*)(W2p + (0 * 64 + lane) * 8);
    wb2[1] = *(const bf16x8*)(W2p + (1 * 64 + lane) * 8);
    wb3[0] = *(const bf16x8*)(W3p + (0 * 64 + lane) * 8);
    wb3[1] = *(const bf16x8*)(W3p + (1 * 64 + lane) * 8);
    wb3[2] = *(const bf16x8*)(W3p + (2 * 64 + lane) * 8);
    float b2c0 = b2[col], b2c1 = b2[16 + col];
    float b3c[3];
    #pragma unroll
    for (int ct = 0; ct < 3; ++ct) {
        int c = ct * 16 + col;
        b3c[ct] = (c < 33) ? b3[c] : 0.f;
    }

    // lane's AT slice (same for both tiles)
    const float4* asl = (const float4*)(AT + ((size_t)s * 64 + b) * 32 + kb * 8);
    float4 a0 = asl[0], a1 = asl[1];

    float aggpart[3] = {0.f, 0.f, 0.f};

    #pragma unroll
    for (int rt = 0; rt < 2; ++rt) {
        int tile = w * 2 + rt;
        int e = tile * 16 + m;
        bool valid = (e < 127);
        int ee = valid ? e : 0;
        int t = ee + (ee >= s);
        float2 st = ((const float2*)statAB)[s * 127 + ee];
        float sc = st.x, sh = st.y;

        const float4* bsl = (const float4*)(BT + ((size_t)t * 64 + b) * 32 + kb * 8);
        float4 bv0 = bsl[0], bv1 = bsl[1];

        float nh[8];
        nh[0] = leakyf((a0.x + bv0.x) * sc + sh);
        nh[1] = leakyf((a0.y + bv0.y) * sc + sh);
        nh[2] = leakyf((a0.z + bv0.z) * sc + sh);
        nh[3] = leakyf((a0.w + bv0.w) * sc + sh);
        nh[4] = leakyf((a1.x + bv1.x) * sc + sh);
        nh[5] = leakyf((a1.y + bv1.y) * sc + sh);
        nh[6] = leakyf((a1.z + bv1.z) * sc + sh);
        nh[7] = leakyf((a1.w + bv1.w) * sc + sh);
        if (!valid) {
            #pragma unroll
            for (int q = 0; q < 8; ++q) nh[q] = 0.f;
        }
        union { bf16x8 v; unsigned u[4]; } AF;
        #pragma unroll
        for (int q = 0; q < 4; ++q) AF.u[q] = pk2bf(nh[2*q], nh[2*q+1]);

        // GEMM2: h2 tile (C layout)
        f32x4 c0 = {0.f, 0.f, 0.f, 0.f}, c1 = {0.f, 0.f, 0.f, 0.f};
        c0 = __builtin_amdgcn_mfma_f32_16x16x32_bf16(AF.v, wb2[0], c0, 0, 0, 0);
        c1 = __builtin_amdgcn_mfma_f32_16x16x32_bf16(AF.v, wb2[1], c1, 0, 0, 0);

        // C -> A transpose via wave-private swizzled scratch (no barrier);
        // one packed cvt per (c0,c1) pair instead of two manual f2bf
        #pragma unroll
        for (int reg = 0; reg < 4; ++reg) {
            int row = q4 + reg;
            float x = leakyf(c0[reg] + b2c0);
            float y = leakyf(c1[reg] + b2c1);
            unsigned pkxy = pk2bf(x, y);
            int cA = col;            // < 16
            int cB = col + 16;
            Hs[w][row * 32 + (((cA >> 3) ^ (row >> 2)) & 3) * 8 + (cA & 7)] =
                (unsigned short)(pkxy & 0xffffu);
            Hs[w][row * 32 + (((cB >> 3) ^ (row >> 2)) & 3) * 8 + (cB & 7)] =
                (unsigned short)(pkxy >> 16);
        }
        // wave-synchronous read-back (compiler emits lgkmcnt wait)
        bf16x8 a2 = *(const bf16x8*)&Hs[w][m * 32 + ((kb ^ (m >> 2)) & 3) * 8];

        // GEMM3
        f32x4 oo[3];
        #pragma unroll
        for (int ct = 0; ct < 3; ++ct) {
            f32x4 cc = {0.f, 0.f, 0.f, 0.f};
            oo[ct] = __builtin_amdgcn_mfma_f32_16x16x32_bf16(a2, wb3[ct], cc, 0, 0, 0);
        }

        // sigmoid on col 0 (lanes with col==0 hold rows q4+reg), then quad shfl
        float v0 = 0.f, v1 = 0.f, v2 = 0.f, v3 = 0.f;
        int grow0 = tile * 16 + q4;
        if (col == 0) {
            v0 = 1.f / (1.f + __expf(-(oo[0][0] + b3c[0])));
            v1 = 1.f / (1.f + __expf(-(oo[0][1] + b3c[0])));
            v2 = 1.f / (1.f + __expf(-(oo[0][2] + b3c[0])));
            v3 = (grow0 == 124) ? 0.f
               : 1.f / (1.f + __expf(-(oo[0][3] + b3c[0])));
            float* ep = edges_out + (size_t)b * PP + s * 127 + grow0;
            ep[0] = v0; ep[1] = v1; ep[2] = v2;
            if (grow0 != 124) ep[3] = v3;
        }
        float ev0 = __shfl(v0, qbase, 64);
        float ev1 = __shfl(v1, qbase, 64);
        float ev2 = __shfl(v2, qbase, 64);
        float ev3 = __shfl(v3, qbase, 64);

        // agg partials (cols 1..32 of the 48-wide output)
        #pragma unroll
        for (int ct = 0; ct < 3; ++ct) {
            float bb3 = b3c[ct];
            float pt = ev0 * (oo[ct][0] + bb3) + ev1 * (oo[ct][1] + bb3)
                     + ev2 * (oo[ct][2] + bb3) + ev3 * (oo[ct][3] + bb3);
            aggpart[ct] += pt;
        }
    }

    // quad-reduce agg partials (sum over kb groups = rows), store wave slice
    #pragma unroll
    for (int ct = 0; ct < 3; ++ct) {
        float pt = aggpart[ct];
        pt += __shfl_xor(pt, 16, 64);
        pt += __shfl_xor(pt, 32, 64);
        int c = ct * 16 + col;
        if (kb == 0 && c >= 1 && c <= 32) aggbuf[w][c - 1] = pt;
    }
    __syncthreads();                                   // the ONLY barrier

    // f-row tail
    if (tid < 16) {
        size_t row = (size_t)b * 128 + s;
        const float* xrow = inputs + row * 32;
        float acc = bf1[tid];
        #pragma unroll
        for (int k = 0; k < 32; ++k) acc += xrow[k] * Wf1s[k * 16 + tid];
        #pragma unroll
        for (int k = 0; k < 32; ++k) {
            float tot = aggbuf[0][k] + aggbuf[1][k] + aggbuf[2][k] + aggbuf[3][k];
            acc += tot * Wf1s[(32 + k) * 16 + tid];
        }
        f[row * 16 + tid] = acc;
        int bucket = blockIdx.x & 63;
        atomicAdd(&fpartA[bucket * 16 + tid], acc);
        atomicAdd(&fpartB[bucket * 16 + tid], acc * acc);
    }
}

// ============ Kernel 4: f-stats reduce (redundant per block) + out ============
__global__ __launch_bounds__(256) void out_kernel(
    const float* __restrict__ f,
    const float* __restrict__ fpartA, const float* __restrict__ fpartB,
    const float* __restrict__ gf, const float* __restrict__ bef,
    const float* __restrict__ Wf2, const float* __restrict__ bf2,
    float* __restrict__ outp)
{
    __shared__ float Wf2s[512];
    __shared__ float sc[16], sh[16];
    __shared__ float fs[128];

    int tid = threadIdx.x;
    for (int idx = tid; idx < 512; idx += 256) Wf2s[idx] = Wf2[idx];
    if (tid < 16) {
        float S = 0.f, Q = 0.f;
        #pragma unroll
        for (int g = 0; g < 64; ++g) {
            S += fpartA[g * 16 + tid];
            Q += fpartB[g * 16 + tid];
        }
        float mean = S * (1.f / 8192.f);
        float var  = Q * (1.f / 8192.f) - mean * mean;
        float inv  = rsqrtf(var + EPSF);
        float s2   = inv * gf[tid];
        sc[tid] = s2;
        sh[tid] = bef[tid] - mean * s2;
    }
    int row0 = blockIdx.x * 8;
    if (tid < 128) {
        int r = tid >> 4, j = tid & 15;
        fs[r * 16 + j] = f[(size_t)(row0 + r) * 16 + j];
    }
    __syncthreads();

    int rl = tid >> 5, d = tid & 31;
    float acc = bf2[d];
    #pragma unroll
    for (int j = 0; j < 16; ++j) {
        float v = fs[rl * 16 + j] * sc[j] + sh[j];
        v = leakyf(v);
        acc += v * Wf2s[j * 32 + d];
    }
    outp[(size_t)(row0 + rl) * 32 + d] = acc;
}

extern "C" void kernel_launch(void* const* d_in, const int* in_sizes, int n_in,
                              void* d_out, int out_size, void* d_ws, size_t ws_size,
                              hipStream_t stream) {
    const float* inputs = (const float*)d_in[0];
    const float* W1   = (const float*)d_in[3];
    const float* b1   = (const float*)d_in[4];
    const float* g1   = (const float*)d_in[5];
    const float* be1  = (const float*)d_in[6];
    const float* W2   = (const float*)d_in[7];
    const float* b2   = (const float*)d_in[8];
    const float* W3   = (const float*)d_in[9];
    const float* b3   = (const float*)d_in[10];
    const float* Wf1  = (const float*)d_in[11];
    const float* bf1  = (const float*)d_in[12];
    const float* gf   = (const float*)d_in[13];
    const float* bef  = (const float*)d_in[14];
    const float* Wf2  = (const float*)d_in[15];
    const float* bf2  = (const float*)d_in[16];

    float* ws = (float*)d_ws;
    float* AT     = ws;                              // 262144
    float* BT     = ws + 262144;                     // 262144
    unsigned short* ATh = (unsigned short*)(ws + 524288);  // 262144 ush
    unsigned short* BTh = ATh + 262144;                    // 262144 ush
    float* SQp    = ws + 786432;                     // 2048
    float* statAB = ws + 790528;                     // 2*16256 = 32512
    float* f      = ws + 823040;                     // 131072
    float* fpartA = ws + 954112;                     // 1024
    float* fpartB = ws + 955136;                     // 1024
    unsigned short* W2p = (unsigned short*)(ws + 956160);  // 1024 ush
    unsigned short* W3p = W2p + 1024;                      // 1536 ush

    float* edges_out = (float*)d_out;                    // B*P
    float* outp      = edges_out + (size_t)BB * PP;      // B*N*D

    proj_kernel<<<512, 256, 0, stream>>>(inputs, W1, b1, W2, W3,
                                         AT, BT, ATh, BTh, SQp,
                                         W2p, W3p, fpartA, fpartB);
    stats2_kernel<<<64, 256, 0, stream>>>(ATh, BTh, SQp, g1, be1, statAB);
    edges_kernel<<<8192, 256, 0, stream>>>(AT, BT, statAB, W2p, W3p,
                                           b2, b3, inputs, Wf1, bf1,
                                           edges_out, f, fpartA, fpartB);
    out_kernel<<<1024, 256, 0, stream>>>(f, fpartA, fpartB, gf, bef, Wf2, bf2, outp);
}